// Round 1
// baseline (243.645 us; speedup 1.0000x reference)
//
#include <hip/hip_runtime.h>

// Bilateral 5x5 filter, 3 chained passes.
// x: [B=32, C=1, H=512, W=512] fp32; sigma_xyz: [3,2]; sigma_r: [3].
// Pass p: sx = sigma_xyz[p][0] (row axis), sy = sigma_xyz[p][1] (col axis),
//         sr = sigma_r[p].
// w(dr,dc) = exp(-dr^2/(2sx^2) - dc^2/(2sy^2) - (nb-c)^2/(2sr^2))
// out = sum(w*nb)/sum(w); replicate padding at borders.

#define HWIN 2
#define TX   64                     // threads in x
#define TYB  4                      // threads in y
#define PXT  4                      // pixels per thread along x
#define TILE_W (TX * PXT)           // 256 output columns per block
#define LDS_W  (TILE_W + 2*PXT)     // 264: cols x0-4 .. x0+259 (aligned halo)
#define LDS_H  (TYB + 2*HWIN)       // 8 rows: y0-2 .. y0+5

__global__ __launch_bounds__(256)
void bilat_pass(const float* __restrict__ in, float* __restrict__ out,
                const float* __restrict__ sxyz, const float* __restrict__ srr,
                int pass, int H, int W)
{
    // Row stride 264 floats = 1056 B = 66*16 -> every row 16B-aligned.
    __shared__ __align__(16) float tile[LDS_H][LDS_W];

    const int tx = threadIdx.x, ty = threadIdx.y;
    const int x0 = blockIdx.x * TILE_W;
    const int y0 = blockIdx.y * TYB;
    const size_t img_off = (size_t)blockIdx.z * (size_t)H * (size_t)W;
    const float* __restrict__ img = in + img_off;

    // ---- stage tile with replicate clamp (coalesced: lx contiguous) ----
    const int lid = ty * TX + tx;   // 0..255
    #pragma unroll
    for (int i = 0; i < (LDS_W * LDS_H + 255) / 256; ++i) {
        int idx = lid + i * 256;
        if (idx < LDS_W * LDS_H) {
            int ly = idx / LDS_W;
            int lx = idx - ly * LDS_W;
            int gy = y0 + ly - HWIN;
            gy = gy < 0 ? 0 : (gy >= H ? H - 1 : gy);
            int gx = x0 + lx - PXT;          // col 0 of LDS = x0-4
            gx = gx < 0 ? 0 : (gx >= W ? W - 1 : gx);
            tile[ly][lx] = img[(size_t)gy * W + gx];
        }
    }
    __syncthreads();

    // ---- per-pass constants (uniform scalar loads) ----
    const float sx = sxyz[2 * pass + 0];
    const float sy = sxyz[2 * pass + 1];
    const float sr = srr[pass];
    const float cx = 0.5f / (sx * sx);   // row-offset coefficient
    const float cy = 0.5f / (sy * sy);   // col-offset coefficient
    const float cr = 0.5f / (sr * sr);   // range coefficient

    // ---- compute 4 pixels per thread ----
    // center pixels: lds row ty+2, cols PXT*tx+4 .. +7 (16B aligned)
    const float4 cen4 = *(const float4*)&tile[ty + HWIN][PXT * tx + PXT];
    const float cen[4] = {cen4.x, cen4.y, cen4.z, cen4.w};
    float num[4] = {0.f, 0.f, 0.f, 0.f};
    float den[4] = {0.f, 0.f, 0.f, 0.f};

    #pragma unroll
    for (int dr = -HWIN; dr <= HWIN; ++dr) {
        const float* row = &tile[ty + HWIN + dr][PXT * tx];
        const float4 a = *(const float4*)(row);       // cols 4tx .. 4tx+3
        const float4 b = *(const float4*)(row + 4);   // cols 4tx+4 .. +7
        const float4 c = *(const float4*)(row + 8);   // cols 4tx+8 .. +11
        const float win[12] = {a.x, a.y, a.z, a.w,
                               b.x, b.y, b.z, b.w,
                               c.x, c.y, c.z, c.w};
        const float srow = (float)(dr * dr) * cx;
        #pragma unroll
        for (int j = 0; j < 4; ++j) {
            #pragma unroll
            for (int dc = -HWIN; dc <= HWIN; ++dc) {
                const float nb = win[PXT + j + dc];
                const float d  = nb - cen[j];
                // 9 distinct (srow + dc^2*cy) values -> CSE'd by compiler
                const float t  = fmaf(d * d, cr, srow + (float)(dc * dc) * cy);
                const float w  = __expf(-t);
                num[j] = fmaf(w, nb, num[j]);
                den[j] += w;
            }
        }
    }

    const int oy = y0 + ty;
    const int ox = x0 + PXT * tx;
    if (oy < H) {
        if (ox + PXT <= W) {
            float4 o;
            o.x = num[0] / den[0];
            o.y = num[1] / den[1];
            o.z = num[2] / den[2];
            o.w = num[3] / den[3];
            *(float4*)&out[img_off + (size_t)oy * W + ox] = o;
        } else {
            for (int j = 0; j < PXT; ++j)
                if (ox + j < W)
                    out[img_off + (size_t)oy * W + ox + j] = num[j] / den[j];
        }
    }
}

extern "C" void kernel_launch(void* const* d_in, const int* in_sizes, int n_in,
                              void* d_out, int out_size, void* d_ws, size_t ws_size,
                              hipStream_t stream)
{
    const float* x    = (const float*)d_in[0];
    const float* sxyz = (const float*)d_in[1];   // [3,2]
    const float* sr   = (const float*)d_in[2];   // [3]
    float* out = (float*)d_out;
    float* tmp = (float*)d_ws;                   // needs BC*H*W*4 = 33.5 MB

    const int H = 512, W = 512;
    const int BC = in_sizes[0] / (H * W);        // 32

    dim3 block(TX, TYB);
    dim3 grid((W + TILE_W - 1) / TILE_W, (H + TYB - 1) / TYB, BC);

    // pass 0: x -> out ; pass 1: out -> tmp ; pass 2: tmp -> out
    bilat_pass<<<grid, block, 0, stream>>>(x,   out, sxyz, sr, 0, H, W);
    bilat_pass<<<grid, block, 0, stream>>>(out, tmp, sxyz, sr, 1, H, W);
    bilat_pass<<<grid, block, 0, stream>>>(tmp, out, sxyz, sr, 2, H, W);
}